// Round 7
// baseline (487.554 us; speedup 1.0000x reference)
//
#include <hip/hip_runtime.h>
#include <hip/hip_bf16.h>

#define M 8192
#define N 8192
#define K 1024
#define BM 256
#define BN 256
#define BK 16
#define KT (K/BK)   // 64 k-steps

typedef __attribute__((ext_vector_type(8))) short short8;
typedef __attribute__((ext_vector_type(4))) float f32x4;
typedef __attribute__((ext_vector_type(16))) float f32x16;

#define MFMA32(a,b,c) __builtin_amdgcn_mfma_f32_32x32x16_bf16((a),(b),(c),0,0,0)

__device__ inline short f2bf(float x){
    __hip_bfloat16 h = __float2bfloat16(x);
    short s; __builtin_memcpy(&s, &h, 2); return s;
}
__device__ inline float bf2f(short s){
    __hip_bfloat16 h; __builtin_memcpy(&h, &s, 2);
    return __bfloat162float(h);
}

__device__ inline void conv8(float4 x0, float4 x1, short8& hi, short8& lo){
    float xs[8] = {x0.x,x0.y,x0.z,x0.w,x1.x,x1.y,x1.z,x1.w};
    #pragma unroll
    for (int j=0;j<8;++j){
        short h = f2bf(xs[j]);
        float r = xs[j] - bf2f(h);
        hi[j] = h; lo[j] = f2bf(r);
    }
}

#define GLOAD_LDS16(gp, lp) \
    __builtin_amdgcn_global_load_lds((const __attribute__((address_space(1))) void*)(gp), \
                                     (__attribute__((address_space(3))) void*)(lp), 16, 0, 0)

// ---------------- K0: presplit f32 -> (hi, lo) bf16 in TRANSPOSED [k8][row] layout ----
__global__ __launch_bounds__(512) void presplit_t(
    const float* __restrict__ A, const float* __restrict__ B,
    short* __restrict__ Aht, short* __restrict__ Alt,
    short* __restrict__ Bht, short* __restrict__ Blt)
{
    size_t c = (size_t)blockIdx.x * 512 + threadIdx.x;
    const float* src; short *dh, *dl;
    const size_t perMat = (size_t)M * (K/8); // 1048576 granules per matrix
    if (c < perMat){ src = A; dh = Aht; dl = Alt; }
    else { c -= perMat; src = B; dh = Bht; dl = Blt; }
    int row = (int)(c >> 7);      // / (K/8)
    int k8  = (int)(c & 127);
    const float* p = src + (size_t)row * K + k8 * 8;
    float4 x0 = *(const float4*)p;
    float4 x1 = *(const float4*)(p + 4);
    short8 hi, lo; conv8(x0, x1, hi, lo);
    size_t o = ((size_t)k8 * M + row) * 8;
    *(short8*)(dh + o) = hi;
    *(short8*)(dl + o) = lo;
}

// ---------------- K1: split-bf16 GEMM C = A * B^T ----------------
// 256x256 tile, 8 waves (2x4) of 128x64, 32x32x16 MFMA, BK=16.
// T4 counted-vmcnt schedule: 4-buffer LDS ring, prefetch depth 2 (stage kt+2 while
// computing kt), vmcnt(4) at iter end -> tile kt+1 ready, loads never drained to 0.
// 2 template phases per K-step: {ds_read || stage -> bar -> lgkm0 -> MFMA -> bar}.
__global__ __launch_bounds__(512, 2)
void gemm_t(const short* __restrict__ Aht, const short* __restrict__ Alt,
            const short* __restrict__ Bht, const short* __restrict__ Blt,
            float* __restrict__ C)
{
    __shared__ __align__(16) short lds[4][4][2][BM][8];   // 4 bufs x 4 arr x 2 slots -> 128 KB

    const int tid  = threadIdx.x;
    const int lane = tid & 63, wid = tid >> 6;

    // bijective XCD chunking: 1024 blocks = 8 xcd x 128; per chunk: 4 block-rows x 32 cols
    const int xcd = blockIdx.x & 7;
    const int gid = xcd * 128 + (blockIdx.x >> 3);
    const int bm0 = (gid >> 5) * BM;
    const int bn0 = (gid & 31) * BN;

    const int wr = wid >> 2, wc = wid & 3;      // 2x4 wave grid; wave tile 128x64
    const int fr = lane & 31;                   // row within a 32-tile
    const int fg = lane >> 5;                   // k-granule half (0/1) = LDS slot

    // staging role: wave pair (wid>>1) owns one array; wid&1 selects slot
    const int arr = wid >> 1;
    const short* gp = (arr == 0) ? Aht : (arr == 1) ? Alt : (arr == 2) ? Bht : Blt;
    const int   gb  = (arr < 2) ? bm0 : bn0;
    const int   sl  = wid & 1;

    f32x16 acc[4][2] = {};

    auto STAGE2 = [&](int buf, int kt, int i0){
        #pragma unroll
        for (int ii = 0; ii < 2; ++ii){
            int i = i0 + ii;
            const short* src = gp + (((size_t)(kt * 2 + sl)) * M + gb + i * 64 + lane) * 8;
            GLOAD_LDS16(src, &lds[buf][arr][sl][i * 64][0]);   // dest: uniform base + lane*16
        }
    };

    // prologue: stage tiles 0,1,2 (12 loads); wait tile0 (tiles 1,2 = 8 outstanding)
    STAGE2(0, 0, 0); STAGE2(0, 0, 2);
    STAGE2(1, 1, 0); STAGE2(1, 1, 2);
    STAGE2(2, 2, 0); STAGE2(2, 2, 2);
    asm volatile("s_waitcnt vmcnt(8)" ::: "memory");
    __builtin_amdgcn_s_barrier();

    for (int kt = 0; kt < KT; ++kt){
        const int cur = kt & 3;
        const int nxt = (kt + 2) & 3;
        const bool doStage = (kt < KT - 2);

        // ================= phase A : m = 0,1 =================
        short8 bh0, bl0, bh1, bl1, ah0, al0, ah1, al1;
        {
            int rb0 = wc * 64 + fr, rb1 = wc * 64 + 32 + fr;
            bh0 = *(const short8*)&lds[cur][2][fg][rb0][0];
            bl0 = *(const short8*)&lds[cur][3][fg][rb0][0];
            bh1 = *(const short8*)&lds[cur][2][fg][rb1][0];
            bl1 = *(const short8*)&lds[cur][3][fg][rb1][0];
            int r0 = wr * 128 + fr;
            ah0 = *(const short8*)&lds[cur][0][fg][r0][0];
            al0 = *(const short8*)&lds[cur][1][fg][r0][0];
            ah1 = *(const short8*)&lds[cur][0][fg][r0 + 32][0];
            al1 = *(const short8*)&lds[cur][1][fg][r0 + 32][0];
        }
        if (doStage) STAGE2(nxt, kt + 2, 0);

        __builtin_amdgcn_s_barrier();
        asm volatile("s_waitcnt lgkmcnt(0)" ::: "memory");
        __builtin_amdgcn_sched_barrier(0);
        __builtin_amdgcn_s_setprio(1);
        acc[0][0] = MFMA32(ah0, bh0, acc[0][0]);
        acc[0][0] = MFMA32(ah0, bl0, acc[0][0]);
        acc[0][0] = MFMA32(al0, bh0, acc[0][0]);
        acc[0][1] = MFMA32(ah0, bh1, acc[0][1]);
        acc[0][1] = MFMA32(ah0, bl1, acc[0][1]);
        acc[0][1] = MFMA32(al0, bh1, acc[0][1]);
        acc[1][0] = MFMA32(ah1, bh0, acc[1][0]);
        acc[1][0] = MFMA32(ah1, bl0, acc[1][0]);
        acc[1][0] = MFMA32(al1, bh0, acc[1][0]);
        acc[1][1] = MFMA32(ah1, bh1, acc[1][1]);
        acc[1][1] = MFMA32(ah1, bl1, acc[1][1]);
        acc[1][1] = MFMA32(al1, bh1, acc[1][1]);
        __builtin_amdgcn_s_setprio(0);
        __builtin_amdgcn_s_barrier();

        // ================= phase B : m = 2,3 =================
        short8 ah2, al2, ah3, al3;
        {
            int r2 = wr * 128 + 64 + fr;
            ah2 = *(const short8*)&lds[cur][0][fg][r2][0];
            al2 = *(const short8*)&lds[cur][1][fg][r2][0];
            ah3 = *(const short8*)&lds[cur][0][fg][r2 + 32][0];
            al3 = *(const short8*)&lds[cur][1][fg][r2 + 32][0];
        }
        if (doStage) STAGE2(nxt, kt + 2, 2);

        __builtin_amdgcn_s_barrier();
        asm volatile("s_waitcnt lgkmcnt(0)" ::: "memory");
        __builtin_amdgcn_sched_barrier(0);
        __builtin_amdgcn_s_setprio(1);
        acc[2][0] = MFMA32(ah2, bh0, acc[2][0]);
        acc[2][0] = MFMA32(ah2, bl0, acc[2][0]);
        acc[2][0] = MFMA32(al2, bh0, acc[2][0]);
        acc[2][1] = MFMA32(ah2, bh1, acc[2][1]);
        acc[2][1] = MFMA32(ah2, bl1, acc[2][1]);
        acc[2][1] = MFMA32(al2, bh1, acc[2][1]);
        acc[3][0] = MFMA32(ah3, bh0, acc[3][0]);
        acc[3][0] = MFMA32(ah3, bl0, acc[3][0]);
        acc[3][0] = MFMA32(al3, bh0, acc[3][0]);
        acc[3][1] = MFMA32(ah3, bh1, acc[3][1]);
        acc[3][1] = MFMA32(ah3, bl1, acc[3][1]);
        acc[3][1] = MFMA32(al3, bh1, acc[3][1]);
        __builtin_amdgcn_s_setprio(0);

        // counted vmcnt: tile kt+1 must be ready; tile kt+2's 4 loads may stay in flight
        if (kt < KT - 2)       asm volatile("s_waitcnt vmcnt(4)" ::: "memory");
        else if (kt == KT - 2) asm volatile("s_waitcnt vmcnt(0)" ::: "memory");
        __builtin_amdgcn_s_barrier();
    }

    // Epilogue: 32x32 C/D layout col=lane&31, row=(reg&3)+8*(reg>>2)+4*(lane>>5)
    // (verified passing in rounds 5-6)
    #pragma unroll
    for (int m = 0; m < 4; ++m){
        #pragma unroll
        for (int n = 0; n < 2; ++n){
            #pragma unroll
            for (int g = 0; g < 4; ++g){
                #pragma unroll
                for (int r = 0; r < 4; ++r){
                    int row = r + 8 * g + 4 * fg;
                    C[(size_t)(bm0 + wr * 128 + m * 32 + row) * N
                      + bn0 + wc * 64 + n * 32 + fr] = acc[m][n][g * 4 + r];
                }
            }
        }
    }
}

// ---------------- K1b: fallback GEMM (no ws): reg-staged f32 on-the-fly split ----------
#define FBM 128
#define FBN 128
#define FBK 64
#define FARR (FBM*FBK)
__global__ __launch_bounds__(256, 2)
void gemm_fb(const float* __restrict__ A, const float* __restrict__ B,
             float* __restrict__ C)
{
    __shared__ __align__(16) short sAh[FARR];
    __shared__ __align__(16) short sAl[FARR];
    __shared__ __align__(16) short sBh[FARR];
    __shared__ __align__(16) short sBl[FARR];

    const int tid  = threadIdx.x;
    const int lane = tid & 63, wid = tid >> 6;
    const int bm0 = blockIdx.y * FBM, bn0 = blockIdx.x * FBN;
    const int wr = wid >> 1, wc = wid & 1;
    const int fr = lane & 15, fg = lane >> 4;

    f32x4 acc[4][4] = {};

    for (int kt = 0; kt < K/FBK; ++kt){
        #pragma unroll
        for (int i = 0; i < 4; ++i){
            int s = tid + i * 256;
            int row = s >> 3, sp = s & 7;
            int widx = row * FBK + ((sp ^ (row & 7)) << 3);
            const float* ga = A + (size_t)(bm0 + row) * K + kt * FBK + sp * 8;
            float4 a0 = *(const float4*)ga, a1 = *(const float4*)(ga + 4);
            short8 hi, lo;
            conv8(a0, a1, hi, lo);
            *(short8*)&sAh[widx] = hi;
            *(short8*)&sAl[widx] = lo;
            const float* gbp = B + (size_t)(bn0 + row) * K + kt * FBK + sp * 8;
            float4 b0 = *(const float4*)gbp, b1 = *(const float4*)(gbp + 4);
            conv8(b0, b1, hi, lo);
            *(short8*)&sBh[widx] = hi;
            *(short8*)&sBl[widx] = lo;
        }
        __syncthreads();

        #pragma unroll
        for (int ks = 0; ks < 2; ++ks){
            short8 ah[4], al[4], bh[4], bl[4];
            #pragma unroll
            for (int m = 0; m < 4; ++m){
                int row = wr * 64 + m * 16 + fr;
                int idx = row * FBK + ((((ks << 2) | fg) ^ (row & 7)) << 3);
                ah[m] = *(const short8*)&sAh[idx];
                al[m] = *(const short8*)&sAl[idx];
            }
            #pragma unroll
            for (int n = 0; n < 4; ++n){
                int row = wc * 64 + n * 16 + fr;
                int idx = row * FBK + ((((ks << 2) | fg) ^ (row & 7)) << 3);
                bh[n] = *(const short8*)&sBh[idx];
                bl[n] = *(const short8*)&sBl[idx];
            }
            #pragma unroll
            for (int m = 0; m < 4; ++m){
                #pragma unroll
                for (int n = 0; n < 4; ++n){
                    acc[m][n] = __builtin_amdgcn_mfma_f32_16x16x32_bf16(ah[m], bh[n], acc[m][n], 0, 0, 0);
                    acc[m][n] = __builtin_amdgcn_mfma_f32_16x16x32_bf16(ah[m], bl[n], acc[m][n], 0, 0, 0);
                    acc[m][n] = __builtin_amdgcn_mfma_f32_16x16x32_bf16(al[m], bh[n], acc[m][n], 0, 0, 0);
                }
            }
        }
        __syncthreads();
    }

    #pragma unroll
    for (int m = 0; m < 4; ++m){
        int grow = bm0 + wr * 64 + m * 16 + fg * 4;
        #pragma unroll
        for (int r = 0; r < 4; ++r){
            float* crow = C + (size_t)(grow + r) * N + bn0 + wc * 64 + fr;
            #pragma unroll
            for (int n = 0; n < 4; ++n)
                crow[n * 16] = acc[m][n][r];
        }
    }
}

// ---------------- K2: fused row softmax (row lives in registers) ----------------
__global__ __launch_bounds__(256) void softmax_fused(float* __restrict__ E)
{
    const int row = blockIdx.x;
    const int tid = threadIdx.x;
    const int lane = tid & 63, wid = tid >> 6;
    float4* rp = (float4*)(E + (size_t)row * N);
    float4 v[8];
    float mx = -3.4e38f;
    #pragma unroll
    for (int i = 0; i < 8; ++i){
        v[i] = rp[tid + i * 256];
        mx = fmaxf(mx, fmaxf(fmaxf(v[i].x, v[i].y), fmaxf(v[i].z, v[i].w)));
    }
    #pragma unroll
    for (int off = 32; off; off >>= 1) mx = fmaxf(mx, __shfl_xor(mx, off));
    __shared__ float redm[4], reds[4];
    if (lane == 0) redm[wid] = mx;
    __syncthreads();
    mx = fmaxf(fmaxf(redm[0], redm[1]), fmaxf(redm[2], redm[3]));
    float s = 0.f;
    #pragma unroll
    for (int i = 0; i < 8; ++i){
        v[i].x = __expf(v[i].x - mx); v[i].y = __expf(v[i].y - mx);
        v[i].z = __expf(v[i].z - mx); v[i].w = __expf(v[i].w - mx);
        s += v[i].x + v[i].y + v[i].z + v[i].w;
    }
    #pragma unroll
    for (int off = 32; off; off >>= 1) s += __shfl_xor(s, off);
    if (lane == 0) reds[wid] = s;
    __syncthreads();
    float inv = 1.0f / (reds[0] + reds[1] + reds[2] + reds[3]);
    #pragma unroll
    for (int i = 0; i < 8; ++i){
        float4 o = v[i];
        o.x *= inv; o.y *= inv; o.z *= inv; o.w *= inv;
        rp[tid + i * 256] = o;
    }
}

extern "C" void kernel_launch(void* const* d_in, const int* in_sizes, int n_in,
                              void* d_out, int out_size, void* d_ws, size_t ws_size,
                              hipStream_t stream)
{
    const float* A = (const float*)d_in[0];  // out_state [M][K]
    const float* B = (const float*)d_in[1];  // history   [N][K]
    float* out = (float*)d_out;

    const size_t elems = (size_t)M * K;                  // 8388608
    const size_t splitBytes = 4 * elems * sizeof(short); // 64 MB

    if (ws_size >= splitBytes){
        short* Aht = (short*)d_ws;
        short* Alt = Aht + elems;
        short* Bht = Alt + elems;
        short* Blt = Bht + elems;
        presplit_t<<<4096, 512, 0, stream>>>(A, B, Aht, Alt, Bht, Blt);
        gemm_t<<<(M/BM)*(N/BN), 512, 0, stream>>>(Aht, Alt, Bht, Blt, out);
    } else {
        gemm_fb<<<dim3(N/FBN, M/FBM), 256, 0, stream>>>(A, B, out);
    }
    softmax_fused<<<M, 256, 0, stream>>>(out);
}

// Round 8
// 482.624 us; speedup vs baseline: 1.0102x; 1.0102x over previous
//
#include <hip/hip_runtime.h>
#include <hip/hip_bf16.h>

#define M 8192
#define N 8192
#define K 1024
#define BM 256
#define BN 256
#define BK 16
#define KT (K/BK)   // 64 k-steps

typedef __attribute__((ext_vector_type(8))) short short8;
typedef __attribute__((ext_vector_type(4))) float f32x4;
typedef __attribute__((ext_vector_type(16))) float f32x16;

#define MFMA32(a,b,c) __builtin_amdgcn_mfma_f32_32x32x16_bf16((a),(b),(c),0,0,0)

__device__ inline short f2bf(float x){
    __hip_bfloat16 h = __float2bfloat16(x);
    short s; __builtin_memcpy(&s, &h, 2); return s;
}
__device__ inline float bf2f(short s){
    __hip_bfloat16 h; __builtin_memcpy(&h, &s, 2);
    return __bfloat162float(h);
}

__device__ inline void conv8(float4 x0, float4 x1, short8& hi, short8& lo){
    float xs[8] = {x0.x,x0.y,x0.z,x0.w,x1.x,x1.y,x1.z,x1.w};
    #pragma unroll
    for (int j=0;j<8;++j){
        short h = f2bf(xs[j]);
        float r = xs[j] - bf2f(h);
        hi[j] = h; lo[j] = f2bf(r);
    }
}

#define GLOAD_LDS16(gp, lp) \
    __builtin_amdgcn_global_load_lds((const __attribute__((address_space(1))) void*)(gp), \
                                     (__attribute__((address_space(3))) void*)(lp), 16, 0, 0)

// ---------------- K0: presplit f32 -> (hi, lo) bf16 in TRANSPOSED [k8][row] layout ----
__global__ __launch_bounds__(512) void presplit_t(
    const float* __restrict__ A, const float* __restrict__ B,
    short* __restrict__ Aht, short* __restrict__ Alt,
    short* __restrict__ Bht, short* __restrict__ Blt)
{
    size_t c = (size_t)blockIdx.x * 512 + threadIdx.x;
    const float* src; short *dh, *dl;
    const size_t perMat = (size_t)M * (K/8); // 1048576 granules per matrix
    if (c < perMat){ src = A; dh = Aht; dl = Alt; }
    else { c -= perMat; src = B; dh = Bht; dl = Blt; }
    int row = (int)(c >> 7);      // / (K/8)
    int k8  = (int)(c & 127);
    const float* p = src + (size_t)row * K + k8 * 8;
    float4 x0 = *(const float4*)p;
    float4 x1 = *(const float4*)(p + 4);
    short8 hi, lo; conv8(x0, x1, hi, lo);
    size_t o = ((size_t)k8 * M + row) * 8;
    *(short8*)(dh + o) = hi;
    *(short8*)(dl + o) = lo;
}

// ---------------- K1: split-bf16 GEMM C = A * B^T ----------------
// 256x256 tile, 8 waves (2x4) of 128x64, 32x32x16 MFMA, BK=16, 4-buffer ring.
// CROSS-ITERATION register pipeline: MFMA(kt) consumes A-fragments read during
// iteration kt-1 (double-buffered registers, static names). One barrier per K-step;
// counted vmcnt(4) (never 0 mid-loop). The 12 ds_reads of step kt+1 issue underneath
// the 24 queued MFMAs of step kt -> LDS pipe overlaps MFMA pipe at last.
__global__ __launch_bounds__(512, 2)
void gemm_t(const short* __restrict__ Aht, const short* __restrict__ Alt,
            const short* __restrict__ Bht, const short* __restrict__ Blt,
            float* __restrict__ C)
{
    __shared__ __align__(16) short lds[4][4][2][BM][8];   // 4 bufs x 4 arr x 2 slots -> 128 KB

    const int tid  = threadIdx.x;
    const int lane = tid & 63, wid = tid >> 6;

    // bijective XCD chunking: 1024 blocks = 8 xcd x 128; per chunk: 4 block-rows x 32 cols
    const int xcd = blockIdx.x & 7;
    const int gid = xcd * 128 + (blockIdx.x >> 3);
    const int bm0 = (gid >> 5) * BM;
    const int bn0 = (gid & 31) * BN;

    const int wr = wid >> 2, wc = wid & 3;      // 2x4 wave grid; wave tile 128x64
    const int fr = lane & 31;                   // row within a 32-tile
    const int fg = lane >> 5;                   // k-granule half (0/1) = LDS slot

    // staging role: wave pair (wid>>1) owns one array; wid&1 selects slot
    const int arr = wid >> 1;
    const short* gp = (arr == 0) ? Aht : (arr == 1) ? Alt : (arr == 2) ? Bht : Blt;
    const int   gb  = (arr < 2) ? bm0 : bn0;
    const int   sl  = wid & 1;

    f32x16 acc[4][2] = {};

    auto STAGE = [&](int buf, int kt){
        #pragma unroll
        for (int i = 0; i < 4; ++i){
            const short* src = gp + (((size_t)(kt * 2 + sl)) * M + gb + i * 64 + lane) * 8;
            GLOAD_LDS16(src, &lds[buf][arr][sl][i * 64][0]);   // dest: uniform base + lane*16
        }
    };

    // A-fragment set (double-buffered across iterations), B-fragment set (per-iteration)
    short8 ah0a, ah1a, ah2a, ah3a, al0a, al1a, al2a, al3a;   // set A
    short8 ah0b, ah1b, ah2b, ah3b, al0b, al1b, al2b, al3b;   // set B
    short8 bh0, bh1, bl0, bl1;

    const int rA = wr * 128 + fr;
    const int rB = wc * 64 + fr;

    #define READ_B(buf) do { \
        bh0 = *(const short8*)&lds[(buf)][2][fg][rB][0];      \
        bl0 = *(const short8*)&lds[(buf)][3][fg][rB][0];      \
        bh1 = *(const short8*)&lds[(buf)][2][fg][rB + 32][0]; \
        bl1 = *(const short8*)&lds[(buf)][3][fg][rB + 32][0]; \
    } while (0)

    #define READ_A(S, buf) do { \
        ah0##S = *(const short8*)&lds[(buf)][0][fg][rA][0];      \
        al0##S = *(const short8*)&lds[(buf)][1][fg][rA][0];      \
        ah1##S = *(const short8*)&lds[(buf)][0][fg][rA + 32][0]; \
        al1##S = *(const short8*)&lds[(buf)][1][fg][rA + 32][0]; \
        ah2##S = *(const short8*)&lds[(buf)][0][fg][rA + 64][0]; \
        al2##S = *(const short8*)&lds[(buf)][1][fg][rA + 64][0]; \
        ah3##S = *(const short8*)&lds[(buf)][0][fg][rA + 96][0]; \
        al3##S = *(const short8*)&lds[(buf)][1][fg][rA + 96][0]; \
    } while (0)

    #define DO_MFMA(S) do { \
        __builtin_amdgcn_s_setprio(1); \
        acc[0][0] = MFMA32(ah0##S, bh0, acc[0][0]); \
        acc[0][0] = MFMA32(ah0##S, bl0, acc[0][0]); \
        acc[0][0] = MFMA32(al0##S, bh0, acc[0][0]); \
        acc[0][1] = MFMA32(ah0##S, bh1, acc[0][1]); \
        acc[0][1] = MFMA32(ah0##S, bl1, acc[0][1]); \
        acc[0][1] = MFMA32(al0##S, bh1, acc[0][1]); \
        acc[1][0] = MFMA32(ah1##S, bh0, acc[1][0]); \
        acc[1][0] = MFMA32(ah1##S, bl0, acc[1][0]); \
        acc[1][0] = MFMA32(al1##S, bh0, acc[1][0]); \
        acc[1][1] = MFMA32(ah1##S, bh1, acc[1][1]); \
        acc[1][1] = MFMA32(ah1##S, bl1, acc[1][1]); \
        acc[1][1] = MFMA32(al1##S, bh1, acc[1][1]); \
        acc[2][0] = MFMA32(ah2##S, bh0, acc[2][0]); \
        acc[2][0] = MFMA32(ah2##S, bl0, acc[2][0]); \
        acc[2][0] = MFMA32(al2##S, bh0, acc[2][0]); \
        acc[2][1] = MFMA32(ah2##S, bh1, acc[2][1]); \
        acc[2][1] = MFMA32(ah2##S, bl1, acc[2][1]); \
        acc[2][1] = MFMA32(al2##S, bh1, acc[2][1]); \
        acc[3][0] = MFMA32(ah3##S, bh0, acc[3][0]); \
        acc[3][0] = MFMA32(ah3##S, bl0, acc[3][0]); \
        acc[3][0] = MFMA32(al3##S, bh0, acc[3][0]); \
        acc[3][1] = MFMA32(ah3##S, bh1, acc[3][1]); \
        acc[3][1] = MFMA32(ah3##S, bl1, acc[3][1]); \
        acc[3][1] = MFMA32(al3##S, bh1, acc[3][1]); \
        __builtin_amdgcn_s_setprio(0); \
    } while (0)

    // Per-iteration body. MFMA(kt) uses A-set read during iter kt-1; B read here (first,
    // so its lgkm wait covers only 4 reads); A-set for kt+1 read after (completes under MFMA).
    #define BODY(kt, CUR, NXT) do { \
        if ((kt) + 2 < KT) asm volatile("s_waitcnt vmcnt(4)" ::: "memory"); \
        else               asm volatile("s_waitcnt vmcnt(0)" ::: "memory"); \
        __builtin_amdgcn_s_barrier(); \
        if ((kt) + 3 < KT) STAGE(((kt) + 3) & 3, (kt) + 3); \
        READ_B((kt) & 3); \
        if ((kt) + 1 < KT) READ_A(NXT, ((kt) + 1) & 3); \
        DO_MFMA(CUR); \
    } while (0)

    // prologue: stage tiles 0,1,2 (12 loads/wave); wait tile0 (8 outstanding); read A(0)
    STAGE(0, 0); STAGE(1, 1); STAGE(2, 2);
    asm volatile("s_waitcnt vmcnt(8)" ::: "memory");
    __builtin_amdgcn_s_barrier();
    READ_A(a, 0);

    for (int kt = 0; kt < KT; kt += 2){
        BODY(kt,     a, b);
        BODY(kt + 1, b, a);
    }

    // Epilogue: 32x32 C/D layout col=lane&31, row=(reg&3)+8*(reg>>2)+4*(lane>>5)
    // (verified passing in rounds 5-7)
    #pragma unroll
    for (int m = 0; m < 4; ++m){
        #pragma unroll
        for (int n = 0; n < 2; ++n){
            #pragma unroll
            for (int g = 0; g < 4; ++g){
                #pragma unroll
                for (int r = 0; r < 4; ++r){
                    int row = r + 8 * g + 4 * fg;
                    C[(size_t)(bm0 + wr * 128 + m * 32 + row) * N
                      + bn0 + wc * 64 + n * 32 + fr] = acc[m][n][g * 4 + r];
                }
            }
        }
    }
    #undef BODY
    #undef DO_MFMA
    #undef READ_A
    #undef READ_B
}

// ---------------- K1b: fallback GEMM (no ws): reg-staged f32 on-the-fly split ----------
#define FBM 128
#define FBN 128
#define FBK 64
#define FARR (FBM*FBK)
__global__ __launch_bounds__(256, 2)
void gemm_fb(const float* __restrict__ A, const float* __restrict__ B,
             float* __restrict__ C)
{
    __shared__ __align__(16) short sAh[FARR];
    __shared__ __align__(16) short sAl[FARR];
    __shared__ __align__(16) short sBh[FARR];
    __shared__ __align__(16) short sBl[FARR];

    const int tid  = threadIdx.x;
    const int lane = tid & 63, wid = tid >> 6;
    const int bm0 = blockIdx.y * FBM, bn0 = blockIdx.x * FBN;
    const int wr = wid >> 1, wc = wid & 1;
    const int fr = lane & 15, fg = lane >> 4;

    f32x4 acc[4][4] = {};

    for (int kt = 0; kt < K/FBK; ++kt){
        #pragma unroll
        for (int i = 0; i < 4; ++i){
            int s = tid + i * 256;
            int row = s >> 3, sp = s & 7;
            int widx = row * FBK + ((sp ^ (row & 7)) << 3);
            const float* ga = A + (size_t)(bm0 + row) * K + kt * FBK + sp * 8;
            float4 a0 = *(const float4*)ga, a1 = *(const float4*)(ga + 4);
            short8 hi, lo;
            conv8(a0, a1, hi, lo);
            *(short8*)&sAh[widx] = hi;
            *(short8*)&sAl[widx] = lo;
            const float* gbp = B + (size_t)(bn0 + row) * K + kt * FBK + sp * 8;
            float4 b0 = *(const float4*)gbp, b1 = *(const float4*)(gbp + 4);
            conv8(b0, b1, hi, lo);
            *(short8*)&sBh[widx] = hi;
            *(short8*)&sBl[widx] = lo;
        }
        __syncthreads();

        #pragma unroll
        for (int ks = 0; ks < 2; ++ks){
            short8 ah[4], al[4], bh[4], bl[4];
            #pragma unroll
            for (int m = 0; m < 4; ++m){
                int row = wr * 64 + m * 16 + fr;
                int idx = row * FBK + ((((ks << 2) | fg) ^ (row & 7)) << 3);
                ah[m] = *(const short8*)&sAh[idx];
                al[m] = *(const short8*)&sAl[idx];
            }
            #pragma unroll
            for (int n = 0; n < 4; ++n){
                int row = wc * 64 + n * 16 + fr;
                int idx = row * FBK + ((((ks << 2) | fg) ^ (row & 7)) << 3);
                bh[n] = *(const short8*)&sBh[idx];
                bl[n] = *(const short8*)&sBl[idx];
            }
            #pragma unroll
            for (int m = 0; m < 4; ++m){
                #pragma unroll
                for (int n = 0; n < 4; ++n){
                    acc[m][n] = __builtin_amdgcn_mfma_f32_16x16x32_bf16(ah[m], bh[n], acc[m][n], 0, 0, 0);
                    acc[m][n] = __builtin_amdgcn_mfma_f32_16x16x32_bf16(ah[m], bl[n], acc[m][n], 0, 0, 0);
                    acc[m][n] = __builtin_amdgcn_mfma_f32_16x16x32_bf16(al[m], bh[n], acc[m][n], 0, 0, 0);
                }
            }
        }
        __syncthreads();
    }

    #pragma unroll
    for (int m = 0; m < 4; ++m){
        int grow = bm0 + wr * 64 + m * 16 + fg * 4;
        #pragma unroll
        for (int r = 0; r < 4; ++r){
            float* crow = C + (size_t)(grow + r) * N + bn0 + wc * 64 + fr;
            #pragma unroll
            for (int n = 0; n < 4; ++n)
                crow[n * 16] = acc[m][n][r];
        }
    }
}

// ---------------- K2: fused row softmax (row lives in registers) ----------------
__global__ __launch_bounds__(256) void softmax_fused(float* __restrict__ E)
{
    const int row = blockIdx.x;
    const int tid = threadIdx.x;
    const int lane = tid & 63, wid = tid >> 6;
    float4* rp = (float4*)(E + (size_t)row * N);
    float4 v[8];
    float mx = -3.4e38f;
    #pragma unroll
    for (int i = 0; i < 8; ++i){
        v[i] = rp[tid + i * 256];
        mx = fmaxf(mx, fmaxf(fmaxf(v[i].x, v[i].y), fmaxf(v[i].z, v[i].w)));
    }
    #pragma unroll
    for (int off = 32; off; off >>= 1) mx = fmaxf(mx, __shfl_xor(mx, off));
    __shared__ float redm[4], reds[4];
    if (lane == 0) redm[wid] = mx;
    __syncthreads();
    mx = fmaxf(fmaxf(redm[0], redm[1]), fmaxf(redm[2], redm[3]));
    float s = 0.f;
    #pragma unroll
    for (int i = 0; i < 8; ++i){
        v[i].x = __expf(v[i].x - mx); v[i].y = __expf(v[i].y - mx);
        v[i].z = __expf(v[i].z - mx); v[i].w = __expf(v[i].w - mx);
        s += v[i].x + v[i].y + v[i].z + v[i].w;
    }
    #pragma unroll
    for (int off = 32; off; off >>= 1) s += __shfl_xor(s, off);
    if (lane == 0) reds[wid] = s;
    __syncthreads();
    float inv = 1.0f / (reds[0] + reds[1] + reds[2] + reds[3]);
    #pragma unroll
    for (int i = 0; i < 8; ++i){
        float4 o = v[i];
        o.x *= inv; o.y *= inv; o.z *= inv; o.w *= inv;
        rp[tid + i * 256] = o;
    }
}

extern "C" void kernel_launch(void* const* d_in, const int* in_sizes, int n_in,
                              void* d_out, int out_size, void* d_ws, size_t ws_size,
                              hipStream_t stream)
{
    const float* A = (const float*)d_in[0];  // out_state [M][K]
    const float* B = (const float*)d_in[1];  // history   [N][K]
    float* out = (float*)d_out;

    const size_t elems = (size_t)M * K;                  // 8388608
    const size_t splitBytes = 4 * elems * sizeof(short); // 64 MB

    if (ws_size >= splitBytes){
        short* Aht = (short*)d_ws;
        short* Alt = Aht + elems;
        short* Bht = Alt + elems;
        short* Blt = Bht + elems;
        presplit_t<<<4096, 512, 0, stream>>>(A, B, Aht, Alt, Bht, Blt);
        gemm_t<<<(M/BM)*(N/BN), 512, 0, stream>>>(Aht, Alt, Bht, Blt, out);
    } else {
        gemm_fb<<<dim3(N/FBN, M/FBM), 256, 0, stream>>>(A, B, out);
    }
    softmax_fused<<<M, 256, 0, stream>>>(out);
}